// Round 12
// baseline (52.604 us; speedup 1.0000x reference)
//
#include <hip/hip_runtime.h>

#define NPART 4096
#define E_TOT 262144
#define HID   128
#define FDOF  6
#define BM    64                 // edges per block-iteration
#define NIT   (E_TOT / BM)       // 4096
#define GRID  2048               // exactly 2 iters/block (4096 = 2*2048)
#define XPAD  40                 // 80 B rows: stride-5 in 16B bank-groups -> conflict-free
#define HPAD  136                // 272 B rows: stride-17 -> conflict-free
#define NCOPY 8                  // partial output copies
#define OUTSZ (NPART * FDOF)     // 24576

typedef __bf16 bf16x8 __attribute__((ext_vector_type(8)));
typedef float  f32x4  __attribute__((ext_vector_type(4)));

__global__ void pairvel_zero_kernel(float* __restrict__ p, int n) {
    const int i = blockIdx.x * blockDim.x + threadIdx.x;
    if (i < n) p[i] = 0.0f;
}

__global__ void pairvel_reduce_kernel(const float* __restrict__ wsp,
                                      float* __restrict__ out) {
    const int i = blockIdx.x * blockDim.x + threadIdx.x;
    if (i < OUTSZ) {
        float s = 0.0f;
        #pragma unroll
        for (int c = 0; c < NCOPY; ++c) s += wsp[c * OUTSZ + i];
        out[i] = s;
    }
}

// Round 12 (base = R6/R11, best structure at ~48 us):
//  - idx (tgt/src) for BOTH iterations loaded in the prologue, coalesced
//    per wave-role -> in-loop gather is a single-step load chain (~900cy,
//    was ~1100+ two-step), issued at start of the L2 phase (longest) so
//    only ~500cy is exposed at barrier C.
//  - depth-2 prefetch removed (R6 audit: it drained ~100cy after issue at
//    barrier D -> fully exposed, pure loss).
//  - GRID 2048 x 2 iters: 8 blocks/CU queued, 4 resident -> block-level
//    pipelining of prologue gathers; exact load balance.
//  - W3 fragments moved to LDS (-16 VGPR, protects 4 waves/SIMD); single
//    X buffer (read at A, written at C); tgts stays double-buffered.
__global__ __launch_bounds__(256) void pairvel_mfma_kernel(
    const float* __restrict__ rel,       // [N,N,3]
    const int*   __restrict__ tgt,       // [E]
    const int*   __restrict__ src,       // [E]
    const float* __restrict__ force,     // [N,6]
    const float* __restrict__ visc,
    const float* __restrict__ medianp,
    const float* __restrict__ contactp,
    const float* __restrict__ W1,        // [19,128]
    const float* __restrict__ b1,        // [128]
    const float* __restrict__ W2,        // [128,128]
    const float* __restrict__ b2,        // [128]
    const float* __restrict__ W3,        // [128,6]
    const float* __restrict__ b3,        // [6]
    float* __restrict__ wsp)             // [NCOPY][N,6] partials
{
    const int tid  = threadIdx.x;
    const int w    = tid >> 6;    // wave 0..3 == gather role (0 geom, 1 f_tgt, 2 f_src)
    const int l    = tid & 63;
    const int l15  = l & 15;
    const int lhi  = l >> 4;
    const int mye  = l;           // edge owned within role (lane-coalesced idx loads)

    float* __restrict__ outc = wsp + (size_t)(blockIdx.x & (NCOPY - 1)) * OUTSZ;

    // ---- weight fragments in registers (B-operand maps, R6-verified) -------
    bf16x8 w1f[2], w2f[4][2];
    #pragma unroll
    for (int nb = 0; nb < 2; ++nb) {
        const int n = (2 * w + nb) * 16 + l15;
        #pragma unroll
        for (int r = 0; r < 8; ++r) {
            const int k = lhi * 8 + r;
            w1f[nb][r] = (k < 19) ? (__bf16)W1[k * HID + n] : (__bf16)0.0f;
        }
    }
    #pragma unroll
    for (int kt = 0; kt < 4; ++kt)
        #pragma unroll
        for (int nb = 0; nb < 2; ++nb) {
            const int n = (2 * w + nb) * 16 + l15;
            #pragma unroll
            for (int r = 0; r < 8; ++r)
                w2f[kt][nb][r] = (__bf16)W2[(kt * 32 + lhi * 8 + r) * HID + n];
        }

    const float b1v0 = b1[(2 * w) * 16 + l15];
    const float b1v1 = b1[(2 * w + 1) * 16 + l15];
    const float b2v0 = b2[(2 * w) * 16 + l15];
    const float b2v1 = b2[(2 * w + 1) * 16 + l15];
    const float b3v  = (l15 < FDOF) ? b3[l15] : 0.0f;
    const float inv_mu  = 1.0f / visc[0];
    const float median  = medianp[0];
    const float contact = contactp[0];

    __shared__ __align__(16) __bf16 Xs[BM][XPAD];      //  5120 B (single buffer)
    __shared__ __align__(16) __bf16 Hs[BM][HPAD];      // 17408 B (H1 then H2)
    __shared__ __align__(16) __bf16 W3L[4][64][8];     //  4096 B
    __shared__ int tgts[2][BM];                        //   512 B

    // ---- stage W3 fragments into LDS (one thread per entry; 4*64=256) ------
    {
        const int kt = tid >> 6, ln = tid & 63;
        const int c  = ln & 15, rh = ln >> 4;
        bf16x8 v;
        #pragma unroll
        for (int r = 0; r < 8; ++r)
            v[r] = (c < FDOF) ? (__bf16)W3[(kt * 32 + rh * 8 + r) * FDOF + c]
                              : (__bf16)0.0f;
        *reinterpret_cast<bf16x8*>(&W3L[kt][ln][0]) = v;
    }

    // zero X pad cols 19..31 once (cols 32..39 never read)
    for (int t = tid; t < BM * 13; t += 256)
        Xs[t / 13][19 + t % 13] = (__bf16)0.0f;

    // ---- prologue: coalesced idx loads for BOTH iterations -----------------
    int tgA = 0, sgA = 0, tgB = 0, sgB = 0;
    if (w < 3) {
        const int eA = blockIdx.x * BM + mye;
        const int eB = (blockIdx.x + GRID) * BM + mye;
        tgA = tgt[eA]; sgA = src[eA];
        tgB = tgt[eB]; sgB = src[eB];
    }

    float p0 = 0.f, p1 = 0.f, p2 = 0.f, p3 = 0.f, p4 = 0.f, p5 = 0.f;

    auto gather_data = [&](int tg, int sg) {
        if (w == 0) {                       // geometry: 12 B from rel
            const float* rp = rel + ((size_t)tg * NPART + sg) * 3;
            p0 = rp[0]; p1 = rp[1]; p2 = rp[2];
        } else if (w == 1) {                // force[tgt]
            const float2* f2 = (const float2*)(force + (size_t)tg * FDOF);
            const float2 u0 = f2[0], u1 = f2[1], u2 = f2[2];
            p0 = u0.x; p1 = u0.y; p2 = u1.x; p3 = u1.y; p4 = u2.x; p5 = u2.y;
        } else if (w == 2) {                // force[src]
            const float2* f2 = (const float2*)(force + (size_t)sg * FDOF);
            const float2 u0 = f2[0], u1 = f2[1], u2 = f2[2];
            p0 = u0.x; p1 = u0.y; p2 = u1.x; p3 = u1.y; p4 = u2.x; p5 = u2.y;
        }
    };

    auto write_x = [&](int b, int tg) {
        if (w == 0) {
            tgts[b][mye] = tg;
            const float dist = fmaxf(sqrtf(p0*p0 + p1*p1 + p2*p2), 1e-8f);
            const float rs = (dist - median) * (dist - median);
            Xs[mye][0] = (__bf16)p0;
            Xs[mye][1] = (__bf16)p1;
            Xs[mye][2] = (__bf16)p2;
            Xs[mye][3] = (__bf16)dist;
            Xs[mye][4] = (__bf16)rs;
            Xs[mye][5] = (__bf16)(rs * rs);
            Xs[mye][6] = (__bf16)(dist - contact);
        } else if (w == 1) {
            Xs[mye][7]  = (__bf16)p0;
            Xs[mye][8]  = (__bf16)p1;
            Xs[mye][9]  = (__bf16)p2;
            Xs[mye][10] = (__bf16)p3;
            Xs[mye][11] = (__bf16)p4;
            Xs[mye][12] = (__bf16)p5;
        } else if (w == 2) {
            Xs[mye][13] = (__bf16)p0;
            Xs[mye][14] = (__bf16)p1;
            Xs[mye][15] = (__bf16)p2;
            Xs[mye][16] = (__bf16)p3;
            Xs[mye][17] = (__bf16)p4;
            Xs[mye][18] = (__bf16)p5;
        }
    };

    gather_data(tgA, sgA);
    write_x(0, tgA);
    int buf = 0;

    #pragma unroll
    for (int ii = 0; ii < 2; ++ii) {
        __syncthreads();   // (A) X/tgts staged; Hs free; W3L ready (ii=0)

        // ---- layer 1: H1 = relu(X @ W1 + b1) -> Hs -------------------------
        #pragma unroll
        for (int m = 0; m < 4; ++m) {
            const bf16x8 a = *reinterpret_cast<const bf16x8*>(
                &Xs[m * 16 + l15][lhi * 8]);
            #pragma unroll
            for (int nb = 0; nb < 2; ++nb) {
                const float bv = nb ? b1v1 : b1v0;
                f32x4 acc = { bv, bv, bv, bv };
                acc = __builtin_amdgcn_mfma_f32_16x16x32_bf16(
                          a, w1f[nb], acc, 0, 0, 0);
                #pragma unroll
                for (int r = 0; r < 4; ++r)
                    Hs[m * 16 + lhi * 4 + r][(2 * w + nb) * 16 + l15] =
                        (__bf16)fmaxf(acc[r], 0.0f);
            }
        }
        __syncthreads();   // (B) H1 ready

        // ---- issue next-iter data gather (single-step; drains at C under L2)
        if (ii == 0) gather_data(tgB, sgB);

        // ---- layer 2: accs = H1 @ W2 + b2 (registers only) -----------------
        f32x4 accs[4][2];
        #pragma unroll
        for (int m = 0; m < 4; ++m) {
            accs[m][0] = (f32x4){ b2v0, b2v0, b2v0, b2v0 };
            accs[m][1] = (f32x4){ b2v1, b2v1, b2v1, b2v1 };
            #pragma unroll
            for (int kt = 0; kt < 4; ++kt) {
                const bf16x8 a = *reinterpret_cast<const bf16x8*>(
                    &Hs[m * 16 + l15][kt * 32 + lhi * 8]);
                accs[m][0] = __builtin_amdgcn_mfma_f32_16x16x32_bf16(
                                 a, w2f[kt][0], accs[m][0], 0, 0, 0);
                accs[m][1] = __builtin_amdgcn_mfma_f32_16x16x32_bf16(
                                 a, w2f[kt][1], accs[m][1], 0, 0, 0);
            }
        }
        __syncthreads();   // (C) H1 reads done; gather arrived

        // ---- write H2 into Hs; stage next X --------------------------------
        #pragma unroll
        for (int m = 0; m < 4; ++m)
            #pragma unroll
            for (int nb = 0; nb < 2; ++nb)
                #pragma unroll
                for (int r = 0; r < 4; ++r)
                    Hs[m * 16 + lhi * 4 + r][(2 * w + nb) * 16 + l15] =
                        (__bf16)fmaxf(accs[m][nb][r], 0.0f);

        if (ii == 0) write_x(buf ^ 1, tgB);
        __syncthreads();   // (D) H2 ready; X staged

        // ---- layer 3: vel = (H2 @ W3 + b3)/mu; wave w -> edges 16w..16w+15 -
        f32x4 acc3 = { 0.0f, 0.0f, 0.0f, 0.0f };
        #pragma unroll
        for (int kt = 0; kt < 4; ++kt) {
            const bf16x8 a = *reinterpret_cast<const bf16x8*>(
                &Hs[w * 16 + l15][kt * 32 + lhi * 8]);
            const bf16x8 wf = *reinterpret_cast<const bf16x8*>(
                &W3L[kt][l][0]);
            acc3 = __builtin_amdgcn_mfma_f32_16x16x32_bf16(
                       a, wf, acc3, 0, 0, 0);
        }
        if (l15 < FDOF) {
            #pragma unroll
            for (int r = 0; r < 4; ++r) {
                const int e = w * 16 + lhi * 4 + r;
                atomicAdd(&outc[(size_t)tgts[buf][e] * FDOF + l15],
                          (acc3[r] + b3v) * inv_mu);
            }
        }
        buf ^= 1;
    }
}

extern "C" void kernel_launch(void* const* d_in, const int* in_sizes, int n_in,
                              void* d_out, int out_size, void* d_ws, size_t ws_size,
                              hipStream_t stream) {
    const float* rel   = (const float*)d_in[0];
    const int*   tgt   = (const int*)d_in[1];
    const int*   src   = (const int*)d_in[2];
    const float* force = (const float*)d_in[3];
    const float* visc  = (const float*)d_in[4];
    const float* med   = (const float*)d_in[5];
    const float* con   = (const float*)d_in[6];
    const float* W1    = (const float*)d_in[7];
    const float* b1    = (const float*)d_in[8];
    const float* W2    = (const float*)d_in[9];
    const float* b2    = (const float*)d_in[10];
    const float* W3    = (const float*)d_in[11];
    const float* b3    = (const float*)d_in[12];
    float* out = (float*)d_out;
    float* wsp = (float*)d_ws;

    const int nws = NCOPY * OUTSZ;
    pairvel_zero_kernel<<<(nws + 255) / 256, 256, 0, stream>>>(wsp, nws);
    pairvel_mfma_kernel<<<GRID, 256, 0, stream>>>(
        rel, tgt, src, force, visc, med, con, W1, b1, W2, b2, W3, b3, wsp);
    pairvel_reduce_kernel<<<(OUTSZ + 255) / 256, 256, 0, stream>>>(wsp, out);
}